// Round 1
// baseline (2887.949 us; speedup 1.0000x reference)
//
#include <hip/hip_runtime.h>
#include <hip/hip_bf16.h>

typedef __hip_bfloat16 bf16;
typedef __attribute__((ext_vector_type(8))) short short8;
typedef __attribute__((ext_vector_type(4))) float f32x4;

__device__ __forceinline__ float to_f(float x) { return x; }
__device__ __forceinline__ float to_f(bf16 x) { return __bfloat162float(x); }
__device__ __forceinline__ float ldp(const void* p, size_t i, bool f32) {
  return f32 ? ((const float*)p)[i] : __bfloat162float(((const bf16*)p)[i]);
}
__device__ __forceinline__ short f2b(float f) {
  bf16 h = __float2bfloat16(f);
  return *reinterpret_cast<short*>(&h);
}

// dtype probe: f32 data read as u16 pairs shows implausible bf16 exponents.
__global__ void detect_kernel(const void* __restrict__ probe,
                              unsigned* __restrict__ flag) {
  __shared__ int sbad;
  if (threadIdx.x == 0) sbad = 0;
  __syncthreads();
  const unsigned short* u = (const unsigned short*)probe;
  int bad = 0;
  for (int i = threadIdx.x; i < 2048; i += 256) {
    unsigned short w = u[i];
    unsigned e = (w >> 7) & 0xFFu;
    bool plaus = (w == 0) || (w == 0x8000u) || (e >= 0x60u && e <= 0x7Eu);
    if (!plaus) bad++;
  }
  atomicAdd(&sbad, bad);
  __syncthreads();
  if (threadIdx.x == 0) *flag = (sbad > 100) ? 1u : 0u;
}

// ---- weight prep: params (f32|bf16) -> bf16 ws; optional transpose ----
#define MAXSEG 24
struct PrepArgs {
  int nseg;
  const void* src[MAXSEG];
  long long soff[MAXSEG];
  short* dst[MAXSEG];
  int scols[MAXSEG];
  int dstride[MAXSEG];
  int transp[MAXSEG];
  long long prefix[MAXSEG + 1];
};
__global__ void prep_kernel(PrepArgs a, const unsigned* __restrict__ dflag) {
  const bool isf32 = (*dflag != 0u);
  long long i = (long long)blockIdx.x * 256 + threadIdx.x;
  if (i >= a.prefix[a.nseg]) return;
  int s = 0;
  while (i >= a.prefix[s + 1]) s++;
  long long loc = i - a.prefix[s];
  long long r = loc / a.scols[s], c = loc % a.scols[s];
  float v = a.src[s] ? ldp(a.src[s], (size_t)(a.soff[s] + loc), isf32) : 0.f;
  long long idx = a.transp[s] ? (c * a.dstride[s] + r) : (r * a.dstride[s] + c);
  a.dst[s][idx] = f2b(v);
}

// ---- multi-job MFMA GEMM, 128x128 tile ----
// C(M,N) = act(A @ WT^T + bias [+ Cin]). A bf16 (lda), optionally gathered.
// WT bf16 [N][Kp] stride wst, zero-padded so K%32==0 needs no tail guard.
// 256 thr = 4 waves in 2x2; wave = 64x64 via 4x4 mfma_16x16x32.
// flags: 1=gather, 4=tanh.
struct GJob {
  const bf16* A;
  const int* rowidx;
  const short* WT;
  const bf16* bias;
  float* Cf;
  bf16* Ch;
  int lda, wst, K, M, N, flags;
  const float* Cin;  // optional f32 C-in, shape (M,N)
};
struct GJobs {
  GJob j[4];
};

__global__ __launch_bounds__(256) void mj_gemm(GJobs args) {
  GJob jb = args.j[blockIdx.z];
  const int n0 = blockIdx.x * 128, m0 = blockIdx.y * 128;
  if (n0 >= jb.N || m0 >= jb.M) return;
  __shared__ short As[128][40];  // [m][k], stride 40: uniform-banked
  __shared__ short Bs[128][40];  // [n][k]
  __shared__ int rows[128];
  const int tid = threadIdx.x, lane = tid & 63, wave = tid >> 6;
  const int srow = tid >> 1, skoff = (tid & 1) * 16;
  const int wr = (wave >> 1) * 64, wc = (wave & 1) * 64;

  if (jb.flags & 1) {
    if (tid < 128) rows[tid] = jb.rowidx[m0 + tid];
    __syncthreads();
  }
  const long long arow =
      (jb.flags & 1) ? (long long)rows[srow] : (long long)(m0 + srow);
  const short* abase = (const short*)jb.A + arow * jb.lda + skoff;
  const short* bbase = jb.WT + (long long)(n0 + srow) * jb.wst + skoff;

  f32x4 acc[4][4];
#pragma unroll
  for (int i = 0; i < 4; i++)
#pragma unroll
    for (int j = 0; j < 4; j++) acc[i][j] = 0.f;

  const int K = jb.K;
  short8 a0 = *(const short8*)(abase);
  short8 a1 = *(const short8*)(abase + 8);
  short8 b0 = *(const short8*)(bbase);
  short8 b1 = *(const short8*)(bbase + 8);

  for (int k0 = 0; k0 < K; k0 += 32) {
    __syncthreads();
    *(short8*)&As[srow][skoff] = a0;
    *(short8*)&As[srow][skoff + 8] = a1;
    *(short8*)&Bs[srow][skoff] = b0;
    *(short8*)&Bs[srow][skoff + 8] = b1;
    __syncthreads();
    int kn = (k0 + 32 < K) ? k0 + 32 : k0;  // clamped prefetch (last unused)
    a0 = *(const short8*)(abase + kn);
    a1 = *(const short8*)(abase + kn + 8);
    b0 = *(const short8*)(bbase + kn);
    b1 = *(const short8*)(bbase + kn + 8);
    short8 af[4], bfr[4];
#pragma unroll
    for (int i = 0; i < 4; i++)
      af[i] = *(short8*)&As[wr + i * 16 + (lane & 15)][(lane >> 4) * 8];
#pragma unroll
    for (int j = 0; j < 4; j++)
      bfr[j] = *(short8*)&Bs[wc + j * 16 + (lane & 15)][(lane >> 4) * 8];
#pragma unroll
    for (int i = 0; i < 4; i++)
#pragma unroll
      for (int j = 0; j < 4; j++)
        acc[i][j] =
            __builtin_amdgcn_mfma_f32_16x16x32_bf16(af[i], bfr[j], acc[i][j],
                                                    0, 0, 0);
  }

  const int N = jb.N;
  const float* cin = jb.Cin;
#pragma unroll
  for (int j = 0; j < 4; j++) {
    int col = n0 + wc + j * 16 + (lane & 15);
    float bv = jb.bias ? to_f(jb.bias[col]) : 0.f;
#pragma unroll
    for (int i = 0; i < 4; i++) {
#pragma unroll
      for (int r = 0; r < 4; r++) {
        int row = m0 + wr + i * 16 + (lane >> 4) * 4 + r;
        float v = acc[i][j][r] + bv;
        if (cin) v += cin[(long long)row * N + col];
        if (jb.flags & 4) v = tanhf(v);
        if (jb.Cf) jb.Cf[(long long)row * N + col] = v;
        if (jb.Ch) jb.Ch[(long long)row * N + col] = __float2bfloat16(v);
      }
    }
  }
}

// encoder dual-direction GRU cell. gi from hoisted buffers (pre-offset to
// this step), gh2 = [gh_f(B,768) | gh_b(B,768)] bf16. dir = blockIdx.y.
__global__ __launch_bounds__(256) void enc_cell(
    const bf16* __restrict__ giFs, const bf16* __restrict__ giBs,
    const bf16* __restrict__ gh2, float* __restrict__ hfb,
    bf16* __restrict__ hbf, bf16* __restrict__ bse, int s) {
  int dir = blockIdx.y, b = blockIdx.x, i = threadIdx.x;
  const bf16* gi = (dir ? giBs : giFs) + (long long)b * 768;
  const bf16* gh = gh2 + ((long long)dir * 2048 + b) * 768;
  float ir = to_f(gi[i]), iz = to_f(gi[256 + i]), in_ = to_f(gi[512 + i]);
  float hr = to_f(gh[i]), hz = to_f(gh[256 + i]), hn = to_f(gh[512 + i]);
  long long hidx = (long long)b * 512 + dir * 256 + i;
  float hv = hfb[hidx];
  float r = 1.f / (1.f + expf(-(ir + hr)));
  float z = 1.f / (1.f + expf(-(iz + hz)));
  float n = tanhf(in_ + r * hn);
  float o = (1.f - z) * n + z * hv;
  hfb[hidx] = o;
  hbf[hidx] = __float2bfloat16(o);
  int pos = dir ? (23 - s) : s;
  bse[(long long)b * (24 * 512) + pos * 512 + dir * 256 + i] =
      __float2bfloat16(o);
}

// decoder GRU cell: gi (B,768) bf16 dynamic part, giE (B,768) hoisted
// emb@Wih[0:300]+bih, ghw (B,1024) bf16 (first 768 = gh).
// xgc stride 768; writes hn into cols 512:768.
__global__ __launch_bounds__(256) void dec_cell(
    const bf16* __restrict__ gi, const bf16* __restrict__ giE,
    const bf16* __restrict__ ghw, float* __restrict__ h_d,
    bf16* __restrict__ hdbf, bf16* __restrict__ xgc) {
  int b = blockIdx.x, i = threadIdx.x;
  const bf16* gib = gi + (long long)b * 768;
  const bf16* geb = giE + (long long)b * 768;
  const bf16* ghb = ghw + (long long)b * 1024;
  float ir = to_f(gib[i]) + to_f(geb[i]);
  float iz = to_f(gib[256 + i]) + to_f(geb[256 + i]);
  float in_ = to_f(gib[512 + i]) + to_f(geb[512 + i]);
  float hr = to_f(ghb[i]), hz = to_f(ghb[256 + i]), hn = to_f(ghb[512 + i]);
  float hv = h_d[(long long)b * 256 + i];
  float r = 1.f / (1.f + expf(-(ir + hr)));
  float z = 1.f / (1.f + expf(-(iz + hz)));
  float n = tanhf(in_ + r * hn);
  float o = (1.f - z) * n + z * hv;
  h_d[(long long)b * 256 + i] = o;
  hdbf[(long long)b * 256 + i] = __float2bfloat16(o);
  xgc[(long long)b * 768 + 512 + i] = __float2bfloat16(o);
}

// attention. hWh = ghw[:,768:1024]. Writes xgc[:,0:512]=weighted (stride 768).
__global__ __launch_bounds__(256) void attn_kernel(
    const bf16* __restrict__ ghw, const bf16* __restrict__ proj,
    const bf16* __restrict__ bse, const void* __restrict__ v,
    bf16* __restrict__ xgc, const unsigned* __restrict__ dflag) {
  const bool isf32 = (*dflag != 0u);
  int b = blockIdx.x, tid = threadIdx.x;
  int wave = tid >> 6, lane = tid & 63;
  __shared__ float partial[24][4];
  __shared__ float aw[24];
  float vh = to_f(ghw[(long long)b * 1024 + 768 + tid]);
  float vv = ldp(v, tid, isf32);
  const bf16* pb = proj + (long long)b * 24 * 256;
#pragma unroll 4
  for (int s = 0; s < 24; s++) {
    float e = tanhf(vh + __bfloat162float(pb[s * 256 + tid]));
    float t = vv * e;
#pragma unroll
    for (int off = 32; off > 0; off >>= 1) t += __shfl_down(t, off, 64);
    if (lane == 0) partial[s][wave] = t;
  }
  __syncthreads();
  if (tid == 0) {
    float sc[24];
    float mx = -1e30f;
    for (int s = 0; s < 24; s++) {
      float xv = partial[s][0] + partial[s][1] + partial[s][2] + partial[s][3];
      sc[s] = xv;
      mx = fmaxf(mx, xv);
    }
    float sum = 0.f;
    for (int s = 0; s < 24; s++) {
      sc[s] = expf(sc[s] - mx);
      sum += sc[s];
    }
    float inv = 1.f / sum;
    for (int s = 0; s < 24; s++) aw[s] = sc[s] * inv;
  }
  __syncthreads();
  const bf16* eb = bse + (long long)b * 24 * 512;
  float w0 = 0.f, w1 = 0.f;
#pragma unroll 4
  for (int s = 0; s < 24; s++) {
    float a = aw[s];
    w0 += a * __bfloat162float(eb[s * 512 + tid]);
    w1 += a * __bfloat162float(eb[s * 512 + 256 + tid]);
  }
  bf16* xb = xgc + (long long)b * 768;
  xb[tid] = __float2bfloat16(w0);
  xb[256 + tid] = __float2bfloat16(w1);
}

__global__ void sentinel_kernel(float* out, int n) {
  int i = blockIdx.x * 256 + threadIdx.x;
  if (i < n) out[i] = 123.0f;
}

extern "C" void kernel_launch(void* const* d_in, const int* in_sizes, int n_in,
                              void* d_out, int out_size, void* d_ws,
                              size_t ws_size, hipStream_t stream) {
  const int B = 2048, S = 24, T = 25, VOUT = 128;
  const int* src = (const int*)d_in[0];
  const int* trg = (const int*)d_in[1];
  const void* enc_emb = d_in[2];
  const void* enc_Wih_f = d_in[3];
  const void* enc_Whh_f = d_in[4];
  const void* enc_bih_f = d_in[5];
  const void* enc_bhh_f = d_in[6];
  const void* enc_Wih_b = d_in[7];
  const void* enc_Whh_b = d_in[8];
  const void* enc_bih_b = d_in[9];
  const void* enc_bhh_b = d_in[10];
  const void* enc_fcW = d_in[11];
  const void* enc_fcb = d_in[12];
  const void* attn_Wh = d_in[13];
  const void* attn_We = d_in[14];
  const void* attn_b = d_in[15];
  const void* attn_v = d_in[16];
  const void* dec_emb = d_in[17];
  const void* dec_Wih = d_in[18];
  const void* dec_Whh = d_in[19];
  const void* dec_bih = d_in[20];
  const void* dec_bhh = d_in[21];
  const void* fcW = d_in[22];
  const void* fcb = d_in[23];
  float* out = (float*)d_out;

  // ---- workspace layout ----
  size_t need = 0;
  auto place = [&](size_t bytes) {
    size_t off = need;
    need += (bytes + 255) & ~(size_t)255;
    return off;
  };
  size_t o_flag = place(256);
  size_t o_wstart = need;  // memset-0 region start
  size_t oEmbE = place(64 * 320 * 2);    // enc_emb bf16, k-pad 320
  size_t oEmbD = place(128 * 320 * 2);   // dec_emb bf16
  size_t oWT1 = place(768 * 320 * 2);    // enc_Wih_f^T [768][320]
  size_t oWT2 = place(768 * 256 * 2);    // enc_Whh_f^T
  size_t oWT3 = place(768 * 320 * 2);    // enc_Wih_b^T
  size_t oWT4 = place(768 * 256 * 2);    // enc_Whh_b^T
  size_t oWT5 = place(256 * 512 * 2);    // enc_fcW^T
  size_t oWT6 = place(256 * 512 * 2);    // attn_We^T
  size_t oWcT = place(1024 * 256 * 2);   // [dec_Whh | attn_Wh]^T
  size_t oW7aT = place(768 * 320 * 2);   // dec_Wih[0:300]^T  [768][320]
  size_t oW7bT = place(768 * 512 * 2);   // dec_Wih[300:812]^T [768][512]
  size_t oW8aT = place(128 * 320 * 2);   // fcW[768:1068]^T (emb) [128][320]
  size_t oW8bT = place(128 * 768 * 2);   // fcW k-perm [weighted|hn] [128][768]
  size_t oB1 = place(768 * 2), oB2 = place(768 * 2);
  size_t oB3 = place(768 * 2), oB4 = place(768 * 2);
  size_t oB5 = place(256 * 2), oB6 = place(256 * 2);
  size_t oB7 = place(768 * 2), oBc = place(1024 * 2), oB8 = place(128 * 2);
  size_t o_wend = need;
  size_t o_bse = place((size_t)B * S * 512 * 2);
  size_t o_proj = place((size_t)B * S * 256 * 2);
  size_t o_U = place((size_t)4 * B * 768 * 2);
  size_t o_hfb = place((size_t)B * 512 * 4);
  size_t o_hbf = place((size_t)B * 512 * 2);
  size_t o_hd = place((size_t)B * 256 * 4);
  size_t o_hdbf = place((size_t)B * 256 * 2);
  // hoisted input projections. Encoder lifetime only; decoder hoists alias.
  size_t o_giF = place((size_t)S * B * 768 * 2);  // 75.5 MB
  size_t o_giB = place((size_t)S * B * 768 * 2);  // 75.5 MB

  if (ws_size < need) {
    sentinel_kernel<<<(out_size + 255) / 256, 256, 0, stream>>>(out, out_size);
    return;
  }

  char* base = (char*)d_ws;
  unsigned* dflag = (unsigned*)(base + o_flag);
  bf16* embE = (bf16*)(base + oEmbE);
  bf16* embD = (bf16*)(base + oEmbD);
  short* WT1 = (short*)(base + oWT1);
  short* WT2 = (short*)(base + oWT2);
  short* WT3 = (short*)(base + oWT3);
  short* WT4 = (short*)(base + oWT4);
  short* WT5 = (short*)(base + oWT5);
  short* WT6 = (short*)(base + oWT6);
  short* WcT = (short*)(base + oWcT);
  short* W7aT = (short*)(base + oW7aT);
  short* W7bT = (short*)(base + oW7bT);
  short* W8aT = (short*)(base + oW8aT);
  short* W8bT = (short*)(base + oW8bT);
  bf16 *B1 = (bf16*)(base + oB1), *B2 = (bf16*)(base + oB2);
  bf16 *B3 = (bf16*)(base + oB3), *B4 = (bf16*)(base + oB4);
  bf16 *B5 = (bf16*)(base + oB5), *B6 = (bf16*)(base + oB6);
  bf16 *B7 = (bf16*)(base + oB7), *Bc = (bf16*)(base + oBc);
  bf16* B8 = (bf16*)(base + oB8);
  bf16* bse = (bf16*)(base + o_bse);
  bf16* proj = (bf16*)(base + o_proj);
  bf16* U = (bf16*)(base + o_U);
  float* hfb = (float*)(base + o_hfb);
  bf16* hbf = (bf16*)(base + o_hbf);
  float* h_d = (float*)(base + o_hd);
  bf16* hdbf = (bf16*)(base + o_hdbf);
  bf16* giF = (bf16*)(base + o_giF);  // enc fwd x@Wih_f+bih_f, [S*B][768]
  bf16* giB = (bf16*)(base + o_giB);  // enc bwd x@Wih_b+bih_b, [S*B][768]
  // decoder hoists alias encoder gi buffers (dead after encoder loop):
  bf16* giE = (bf16*)(base + o_giF);   // emb@dec_Wih[0:300]+bih [T-1*B][768]
  float* fcE = (float*)(base + o_giB); // emb@fcW[768:1068]+fcb  [T-1*B][128] f32
  // decoder overlay inside U (encoder uses only first 2*B*768 for gh):
  bf16* gi = U;                                        // (B,768) dynamic
  bf16* ghw = U + (size_t)B * 768;                     // (B,1024)
  bf16* xgc = U + (size_t)B * 768 + (size_t)B * 1024;  // (B,768) [wgt|hn]

  detect_kernel<<<1, 256, 0, stream>>>(enc_emb, dflag);
  (void)hipMemsetAsync(base + o_wstart, 0, o_wend - o_wstart, stream);

  // ---- weight prep ----
  PrepArgs pa;
  int ns = 0;
  long long tot = 0;
  auto seg = [&](const void* s, long long soff, short* dst, int scols,
                 int dstride, int transp, long long count) {
    pa.src[ns] = s;
    pa.soff[ns] = soff;
    pa.dst[ns] = dst;
    pa.scols[ns] = scols;
    pa.dstride[ns] = dstride;
    pa.transp[ns] = transp;
    pa.prefix[ns] = tot;
    tot += count;
    ns++;
  };
  seg(enc_emb, 0, (short*)embE, 300, 320, 0, 64 * 300);
  seg(dec_emb, 0, (short*)embD, 300, 320, 0, 128 * 300);
  seg(enc_Wih_f, 0, WT1, 768, 320, 1, 230400);
  seg(enc_Whh_f, 0, WT2, 768, 256, 1, 196608);
  seg(enc_Wih_b, 0, WT3, 768, 320, 1, 230400);
  seg(enc_Whh_b, 0, WT4, 768, 256, 1, 196608);
  seg(enc_fcW, 0, WT5, 256, 512, 1, 131072);
  seg(attn_We, 0, WT6, 256, 512, 1, 131072);
  seg(dec_Whh, 0, WcT, 768, 256, 1, 196608);
  seg(attn_Wh, 0, WcT + 768 * 256, 256, 256, 1, 65536);
  seg(dec_Wih, 0, W7aT, 768, 320, 1, 300 * 768);                  // rows 0:300
  seg(dec_Wih, (long long)300 * 768, W7bT, 768, 512, 1, 512 * 768);  // 300:812
  // fc emb part (fcW rows 768:1068), k-pad 320
  seg(fcW, (long long)768 * 128, W8aT, 128, 320, 1, 300 * 128);
  // fc dyn part k-permuted to xgc = [weighted(0:512)|hn(512:768)]
  seg(fcW, (long long)256 * 128, W8bT, 128, 768, 1, 512 * 128);
  seg(fcW, 0, W8bT + 512, 128, 768, 1, 256 * 128);
  seg(enc_bih_f, 0, (short*)B1, 768, 768, 0, 768);
  seg(enc_bhh_f, 0, (short*)B2, 768, 768, 0, 768);
  seg(enc_bih_b, 0, (short*)B3, 768, 768, 0, 768);
  seg(enc_bhh_b, 0, (short*)B4, 768, 768, 0, 768);
  seg(enc_fcb, 0, (short*)B5, 256, 256, 0, 256);
  seg(attn_b, 0, (short*)B6, 256, 256, 0, 256);
  seg(dec_bih, 0, (short*)B7, 768, 768, 0, 768);
  seg(dec_bhh, 0, (short*)Bc, 768, 768, 0, 768);  // Bc[768:1024] stays 0
  seg(fcb, 0, (short*)B8, 128, 128, 0, 128);
  pa.prefix[ns] = tot;
  pa.nseg = ns;
  prep_kernel<<<(int)((tot + 255) / 256), 256, 0, stream>>>(pa, dflag);

  (void)hipMemsetAsync(hfb, 0, (size_t)B * 512 * 4, stream);
  (void)hipMemsetAsync(hbf, 0, (size_t)B * 512 * 2, stream);
  (void)hipMemsetAsync(out, 0, (size_t)B * VOUT * 4, stream);  // outputs[0]=0

  auto launch = [&](const GJob* jobs, int nj, int gx, int gy) {
    GJobs a{};
    for (int i = 0; i < nj; i++) a.j[i] = jobs[i];
    mj_gemm<<<dim3(gx, gy, nj), 256, 0, stream>>>(a);
  };

  // ---- encoder input projections hoisted: one big batched GEMM ----
  // giF[s*B+b] = embE[src[s,b]] @ Wih_f + bih_f  (and bwd into giB)
  {
    GJob j[2];
    j[0] = {embE, src, WT1, B1, nullptr, giF, 320, 320, 320, S * B, 768, 1};
    j[1] = {embE, src, WT3, B3, nullptr, giB, 320, 320, 320, S * B, 768, 1};
    launch(j, 2, 6, 384);
  }

  // ---- encoder: per step only the recurrent gh GEMM + cell ----
  bf16* ghF = U;
  bf16* ghB = U + (size_t)B * 768;
  for (int s = 0; s < S; s++) {
    GJob j[2];
    j[0] = {hbf, nullptr, WT2, B2, nullptr, ghF, 512, 256, 256, B, 768, 0};
    j[1] = {hbf + 256, nullptr, WT4, B4, nullptr, ghB, 512, 256, 256, B, 768,
            0};
    launch(j, 2, 6, 16);
    enc_cell<<<dim3(B, 2), 256, 0, stream>>>(
        giF + (size_t)s * B * 768, giB + (size_t)(S - 1 - s) * B * 768, U, hfb,
        hbf, bse, s);
  }

  // hidden = tanh([h_f,h_b]@enc_fcW+b); proj = bse@attn_We+attn_b;
  // decoder hoists: giE = emb@dec_Wih[0:300]+bih; fcE = emb@fcW[768:]+fcb.
  // (giE/fcE alias giF/giB — dead after the encoder loop above.)
  {
    GJob j[4];
    j[0] = {hbf, nullptr, WT5, B5, h_d, hdbf, 512, 512, 512, B, 256, 4};
    j[1] = {bse, nullptr, WT6, B6, nullptr, proj, 512, 512, 512, B * S, 256,
            0};
    j[2] = {embD, trg, W7aT, B7, nullptr, giE, 320, 320, 320, (T - 1) * B, 768,
            1};
    j[3] = {embD, trg, W8aT, B8, fcE, nullptr, 320, 320, 320, (T - 1) * B, 128,
            1};
    launch(j, 4, 6, 384);
  }

  // ---- decoder ----
  auto wc_job = [&]() -> GJob {
    return {hdbf, nullptr, WcT, Bc, nullptr, ghw, 256, 256, 256, B, 1024, 0};
  };
  {
    GJob j0 = wc_job();
    launch(&j0, 1, 8, 16);
  }
  for (int t = 0; t < T - 1; t++) {
    attn_kernel<<<B, 256, 0, stream>>>(ghw, proj, bse, attn_v, xgc, dflag);
    GJob jw = {xgc, nullptr, W7bT, nullptr, nullptr, gi, 768, 512, 512, B, 768,
               0};
    launch(&jw, 1, 6, 16);
    dec_cell<<<B, 256, 0, stream>>>(gi, giE + (size_t)t * B * 768, ghw, h_d,
                                    hdbf, xgc);
    GJob jf[2];
    jf[0] = {xgc, nullptr, W8bT, nullptr, out + (size_t)(t + 1) * B * VOUT,
             nullptr, 768, 768, 768, B, 128, 0, fcE + (size_t)t * B * 128};
    if (t < T - 2) {
      jf[1] = wc_job();
      launch(jf, 2, 8, 16);
    } else {
      launch(jf, 1, 1, 16);
    }
  }
}

// Round 2
// 2190.496 us; speedup vs baseline: 1.3184x; 1.3184x over previous
//
#include <hip/hip_runtime.h>
#include <hip/hip_bf16.h>

typedef __hip_bfloat16 bf16;
typedef __attribute__((ext_vector_type(8))) short short8;
typedef __attribute__((ext_vector_type(4))) float f32x4;

__device__ __forceinline__ float to_f(float x) { return x; }
__device__ __forceinline__ float to_f(bf16 x) { return __bfloat162float(x); }
__device__ __forceinline__ float ldp(const void* p, size_t i, bool f32) {
  return f32 ? ((const float*)p)[i] : __bfloat162float(((const bf16*)p)[i]);
}
__device__ __forceinline__ short f2b(float f) {
  bf16 h = __float2bfloat16(f);
  return *reinterpret_cast<short*>(&h);
}
// gate-interleave permutation: source col c = g*256+i (g<3,i<256) ->
// col' = 64*(i>>4) + 16*g + (i&15). MFMA frag j==gate in the fused kernel.
__device__ __forceinline__ int perm1024(int c) {
  return ((c & 255) >> 4) * 64 + (c >> 8) * 16 + (c & 15);
}

// dtype probe: f32 data read as u16 pairs shows implausible bf16 exponents.
__global__ void detect_kernel(const void* __restrict__ probe,
                              unsigned* __restrict__ flag) {
  __shared__ int sbad;
  if (threadIdx.x == 0) sbad = 0;
  __syncthreads();
  const unsigned short* u = (const unsigned short*)probe;
  int bad = 0;
  for (int i = threadIdx.x; i < 2048; i += 256) {
    unsigned short w = u[i];
    unsigned e = (w >> 7) & 0xFFu;
    bool plaus = (w == 0) || (w == 0x8000u) || (e >= 0x60u && e <= 0x7Eu);
    if (!plaus) bad++;
  }
  atomicAdd(&sbad, bad);
  __syncthreads();
  if (threadIdx.x == 0) *flag = (sbad > 100) ? 1u : 0u;
}

// ---- weight prep: params (f32|bf16) -> bf16 ws ----
// transp: 0=copy, 1=transpose, 2=transpose+perm1024, 3=copy+perm1024
#define MAXSEG 24
struct PrepArgs {
  int nseg;
  const void* src[MAXSEG];
  long long soff[MAXSEG];
  short* dst[MAXSEG];
  int scols[MAXSEG];
  int dstride[MAXSEG];
  int transp[MAXSEG];
  long long prefix[MAXSEG + 1];
};
__global__ void prep_kernel(PrepArgs a, const unsigned* __restrict__ dflag) {
  const bool isf32 = (*dflag != 0u);
  long long i = (long long)blockIdx.x * 256 + threadIdx.x;
  if (i >= a.prefix[a.nseg]) return;
  int s = 0;
  while (i >= a.prefix[s + 1]) s++;
  long long loc = i - a.prefix[s];
  long long r = loc / a.scols[s], c = loc % a.scols[s];
  float v = a.src[s] ? ldp(a.src[s], (size_t)(a.soff[s] + loc), isf32) : 0.f;
  int tp = a.transp[s];
  long long idx;
  if (tp == 1)
    idx = c * a.dstride[s] + r;
  else if (tp == 2)
    idx = (long long)perm1024((int)c) * a.dstride[s] + r;
  else if (tp == 3)
    idx = perm1024((int)c);
  else
    idx = r * a.dstride[s] + c;
  a.dst[s][idx] = f2b(v);
}

// ---- multi-job MFMA GEMM, 128x128 tile ----
// C(M,N) = act(A @ WT^T + bias [+ Cin[cinrow]]). flags: 4=tanh.
struct GJob {
  const bf16* A;
  const short* WT;
  const bf16* bias;
  float* Cf;
  bf16* Ch;
  const float* Cin;    // optional f32 addend, stride N
  const int* cinrow;   // optional row gather for Cin
  int lda, wst, K, M, N, flags;
};
struct GJobs {
  GJob j[4];
};

__global__ __launch_bounds__(256) void mj_gemm(GJobs args) {
  GJob jb = args.j[blockIdx.z];
  const int n0 = blockIdx.x * 128, m0 = blockIdx.y * 128;
  if (n0 >= jb.N || m0 >= jb.M) return;
  __shared__ short As[128][40];  // [m][k], stride 40: uniform-banked
  __shared__ short Bs[128][40];  // [n][k]
  const int tid = threadIdx.x, lane = tid & 63, wave = tid >> 6;
  const int srow = tid >> 1, skoff = (tid & 1) * 16;
  const int wr = (wave >> 1) * 64, wc = (wave & 1) * 64;

  const short* abase =
      (const short*)jb.A + (long long)(m0 + srow) * jb.lda + skoff;
  const short* bbase = jb.WT + (long long)(n0 + srow) * jb.wst + skoff;

  f32x4 acc[4][4];
#pragma unroll
  for (int i = 0; i < 4; i++)
#pragma unroll
    for (int j = 0; j < 4; j++) acc[i][j] = 0.f;

  const int K = jb.K;
  short8 a0 = *(const short8*)(abase);
  short8 a1 = *(const short8*)(abase + 8);
  short8 b0 = *(const short8*)(bbase);
  short8 b1 = *(const short8*)(bbase + 8);

  for (int k0 = 0; k0 < K; k0 += 32) {
    __syncthreads();
    *(short8*)&As[srow][skoff] = a0;
    *(short8*)&As[srow][skoff + 8] = a1;
    *(short8*)&Bs[srow][skoff] = b0;
    *(short8*)&Bs[srow][skoff + 8] = b1;
    __syncthreads();
    int kn = (k0 + 32 < K) ? k0 + 32 : k0;  // clamped prefetch (last unused)
    a0 = *(const short8*)(abase + kn);
    a1 = *(const short8*)(abase + kn + 8);
    b0 = *(const short8*)(bbase + kn);
    b1 = *(const short8*)(bbase + kn + 8);
    short8 af[4], bfr[4];
#pragma unroll
    for (int i = 0; i < 4; i++)
      af[i] = *(short8*)&As[wr + i * 16 + (lane & 15)][(lane >> 4) * 8];
#pragma unroll
    for (int j = 0; j < 4; j++)
      bfr[j] = *(short8*)&Bs[wc + j * 16 + (lane & 15)][(lane >> 4) * 8];
#pragma unroll
    for (int i = 0; i < 4; i++)
#pragma unroll
      for (int j = 0; j < 4; j++)
        acc[i][j] =
            __builtin_amdgcn_mfma_f32_16x16x32_bf16(af[i], bfr[j], acc[i][j],
                                                    0, 0, 0);
  }

  const int N = jb.N;
  const float* cin = jb.Cin;
  const int* cri = jb.cinrow;
#pragma unroll
  for (int j = 0; j < 4; j++) {
    int col = n0 + wc + j * 16 + (lane & 15);
    float bv = jb.bias ? to_f(jb.bias[col]) : 0.f;
#pragma unroll
    for (int i = 0; i < 4; i++) {
#pragma unroll
      for (int r = 0; r < 4; r++) {
        int row = m0 + wr + i * 16 + (lane >> 4) * 4 + r;
        float v = acc[i][j][r] + bv;
        if (cin) {
          long long crow = cri ? (long long)cri[row] : (long long)row;
          v += cin[crow * N + col];
        }
        if (jb.flags & 4) v = tanhf(v);
        if (jb.Cf) jb.Cf[(long long)row * N + col] = v;
        if (jb.Ch) jb.Ch[(long long)row * N + col] = __float2bfloat16(v);
      }
    }
  }
}

// ---- fused GEMM + GRU cell. N'=1024 gate-interleaved (perm1024), M=2048.
// grid (8,16,nj). acc frag j = gate. enc: acc=gh (bias=bhh'), gi from table.
// dec: acc=gi_dyn (no bias), gi_static from table, gh from ghw buffer.
struct CJob {
  const bf16* A;       // [2048][lda]
  const short* WT;     // [1024][wst], perm1024 rows
  const bf16* bias;    // [1024] perm1024 or nullptr
  const bf16* gh;      // [2048][1024] (dec) or nullptr (enc)
  const int* tok;      // [2048] token per row
  const bf16* giTab;   // [vocab][768], gate-major g*256+i (incl bih)
  float* hF;           // f32 hidden state
  bf16* hBf;           // bf16 hidden out (enc: next ping-pong buf)
  bf16* out2;          // bse slice (enc) / xgcAll hn slice (dec)
  long long out2s;     // row stride of out2
  int lda, wst, K, hstride, hoff;
};
struct CJobs {
  CJob j[2];
};

__global__ __launch_bounds__(256) void mj_gemm_cell(CJobs args) {
  CJob jb = args.j[blockIdx.z];
  const int n0 = blockIdx.x * 128, m0 = blockIdx.y * 128;
  __shared__ short As[128][40];
  __shared__ short Bs[128][40];
  __shared__ int toks[128];
  const int tid = threadIdx.x, lane = tid & 63, wave = tid >> 6;
  const int srow = tid >> 1, skoff = (tid & 1) * 16;
  const int wr = (wave >> 1) * 64, wcq = (wave & 1) * 64;

  if (tid < 128) toks[tid] = jb.tok[m0 + tid];
  const short* abase =
      (const short*)jb.A + (long long)(m0 + srow) * jb.lda + skoff;
  const short* bbase = jb.WT + (long long)(n0 + srow) * jb.wst + skoff;

  f32x4 acc[4][4];
#pragma unroll
  for (int i = 0; i < 4; i++)
#pragma unroll
    for (int j = 0; j < 4; j++) acc[i][j] = 0.f;

  const int K = jb.K;
  short8 a0 = *(const short8*)(abase);
  short8 a1 = *(const short8*)(abase + 8);
  short8 b0 = *(const short8*)(bbase);
  short8 b1 = *(const short8*)(bbase + 8);

  for (int k0 = 0; k0 < K; k0 += 32) {
    __syncthreads();
    *(short8*)&As[srow][skoff] = a0;
    *(short8*)&As[srow][skoff + 8] = a1;
    *(short8*)&Bs[srow][skoff] = b0;
    *(short8*)&Bs[srow][skoff + 8] = b1;
    __syncthreads();
    int kn = (k0 + 32 < K) ? k0 + 32 : k0;
    a0 = *(const short8*)(abase + kn);
    a1 = *(const short8*)(abase + kn + 8);
    b0 = *(const short8*)(bbase + kn);
    b1 = *(const short8*)(bbase + kn + 8);
    short8 af[4], bfr[4];
#pragma unroll
    for (int i = 0; i < 4; i++)
      af[i] = *(short8*)&As[wr + i * 16 + (lane & 15)][(lane >> 4) * 8];
#pragma unroll
    for (int j = 0; j < 4; j++)
      bfr[j] = *(short8*)&Bs[wcq + j * 16 + (lane & 15)][(lane >> 4) * 8];
#pragma unroll
    for (int i = 0; i < 4; i++)
#pragma unroll
      for (int j = 0; j < 4; j++)
        acc[i][j] =
            __builtin_amdgcn_mfma_f32_16x16x32_bf16(af[i], bfr[j], acc[i][j],
                                                    0, 0, 0);
  }

  // epilogue: each lane owns hid i_h with gates in acc[i][0..2][r]
  const int u = lane & 15, hi4 = (lane >> 4) * 4;
  const int i_h = ((n0 + wcq) >> 6) * 16 + u;
  float b0g = 0.f, b1g = 0.f, b2g = 0.f;
  if (jb.bias) {
    b0g = to_f(jb.bias[n0 + wcq + u]);
    b1g = to_f(jb.bias[n0 + wcq + 16 + u]);
    b2g = to_f(jb.bias[n0 + wcq + 32 + u]);
  }
#pragma unroll
  for (int i = 0; i < 4; i++) {
#pragma unroll
    for (int r = 0; r < 4; r++) {
      int row = m0 + wr + i * 16 + hi4 + r;
      const bf16* gi = jb.giTab + (long long)toks[row - m0] * 768 + i_h;
      float t0 = to_f(gi[0]), t1 = to_f(gi[256]), t2 = to_f(gi[512]);
      float g0 = acc[i][0][r] + b0g, g1 = acc[i][1][r] + b1g,
            g2 = acc[i][2][r] + b2g;
      float ir, iz, in_, hr, hz, hn;
      if (jb.gh) {
        const bf16* gb = jb.gh + (long long)row * 1024 + i_h;
        ir = g0 + t0;
        iz = g1 + t1;
        in_ = g2 + t2;
        hr = to_f(gb[0]);
        hz = to_f(gb[256]);
        hn = to_f(gb[512]);
      } else {
        ir = t0;
        iz = t1;
        in_ = t2;
        hr = g0;
        hz = g1;
        hn = g2;
      }
      long long hidx = (long long)row * jb.hstride + jb.hoff + i_h;
      float hv = jb.hF[hidx];
      float rr = 1.f / (1.f + expf(-(ir + hr)));
      float zz = 1.f / (1.f + expf(-(iz + hz)));
      float nn = tanhf(in_ + rr * hn);
      float o = (1.f - zz) * nn + zz * hv;
      jb.hF[hidx] = o;
      jb.hBf[hidx] = __float2bfloat16(o);
      jb.out2[(long long)row * jb.out2s + i_h] = __float2bfloat16(o);
    }
  }
}

// attention. vh = ghw[:,768:1024]. Writes xgc[:,0:512]=weighted (stride 768).
__global__ __launch_bounds__(256) void attn_kernel(
    const bf16* __restrict__ ghw, const bf16* __restrict__ proj,
    const bf16* __restrict__ bse, const void* __restrict__ v,
    bf16* __restrict__ xgc, const unsigned* __restrict__ dflag) {
  const bool isf32 = (*dflag != 0u);
  int b = blockIdx.x, tid = threadIdx.x;
  int wave = tid >> 6, lane = tid & 63;
  __shared__ float partial[24][4];
  __shared__ float aw[24];
  float vh = to_f(ghw[(long long)b * 1024 + 768 + tid]);
  float vv = ldp(v, tid, isf32);
  const bf16* pb = proj + (long long)b * 24 * 256;
#pragma unroll 4
  for (int s = 0; s < 24; s++) {
    float e = tanhf(vh + __bfloat162float(pb[s * 256 + tid]));
    float t = vv * e;
#pragma unroll
    for (int off = 32; off > 0; off >>= 1) t += __shfl_down(t, off, 64);
    if (lane == 0) partial[s][wave] = t;
  }
  __syncthreads();
  if (tid == 0) {
    float sc[24];
    float mx = -1e30f;
    for (int s = 0; s < 24; s++) {
      float xv = partial[s][0] + partial[s][1] + partial[s][2] + partial[s][3];
      sc[s] = xv;
      mx = fmaxf(mx, xv);
    }
    float sum = 0.f;
    for (int s = 0; s < 24; s++) {
      sc[s] = expf(sc[s] - mx);
      sum += sc[s];
    }
    float inv = 1.f / sum;
    for (int s = 0; s < 24; s++) aw[s] = sc[s] * inv;
  }
  __syncthreads();
  const bf16* eb = bse + (long long)b * 24 * 512;
  float w0 = 0.f, w1 = 0.f;
#pragma unroll 4
  for (int s = 0; s < 24; s++) {
    float a = aw[s];
    w0 += a * __bfloat162float(eb[s * 512 + tid]);
    w1 += a * __bfloat162float(eb[s * 512 + 256 + tid]);
  }
  bf16* xb = xgc + (long long)b * 768;
  xb[tid] = __float2bfloat16(w0);
  xb[256 + tid] = __float2bfloat16(w1);
}

__global__ void sentinel_kernel(float* out, int n) {
  int i = blockIdx.x * 256 + threadIdx.x;
  if (i < n) out[i] = 123.0f;
}

extern "C" void kernel_launch(void* const* d_in, const int* in_sizes, int n_in,
                              void* d_out, int out_size, void* d_ws,
                              size_t ws_size, hipStream_t stream) {
  const int B = 2048, S = 24, T = 25, VOUT = 128;
  const int* src = (const int*)d_in[0];
  const int* trg = (const int*)d_in[1];
  const void* enc_emb = d_in[2];
  const void* enc_Wih_f = d_in[3];
  const void* enc_Whh_f = d_in[4];
  const void* enc_bih_f = d_in[5];
  const void* enc_bhh_f = d_in[6];
  const void* enc_Wih_b = d_in[7];
  const void* enc_Whh_b = d_in[8];
  const void* enc_bih_b = d_in[9];
  const void* enc_bhh_b = d_in[10];
  const void* enc_fcW = d_in[11];
  const void* enc_fcb = d_in[12];
  const void* attn_Wh = d_in[13];
  const void* attn_We = d_in[14];
  const void* attn_b = d_in[15];
  const void* attn_v = d_in[16];
  const void* dec_emb = d_in[17];
  const void* dec_Wih = d_in[18];
  const void* dec_Whh = d_in[19];
  const void* dec_bih = d_in[20];
  const void* dec_bhh = d_in[21];
  const void* fcW = d_in[22];
  const void* fcb = d_in[23];
  float* out = (float*)d_out;

  // ---- workspace layout ----
  size_t need = 0;
  auto place = [&](size_t bytes) {
    size_t off = need;
    need += (bytes + 255) & ~(size_t)255;
    return off;
  };
  size_t o_flag = place(256);
  size_t o_wstart = need;  // memset-0 region start
  size_t oEmbE = place(64 * 320 * 2);     // enc_emb bf16, k-pad 320
  size_t oEmbD = place(128 * 320 * 2);    // dec_emb bf16
  size_t oWT1 = place(768 * 320 * 2);     // enc_Wih_f^T [768][320]
  size_t oWT2 = place(1024 * 256 * 2);    // enc_Whh_f^T perm1024
  size_t oWT3 = place(768 * 320 * 2);     // enc_Wih_b^T
  size_t oWT4 = place(1024 * 256 * 2);    // enc_Whh_b^T perm1024
  size_t oWT5 = place(256 * 512 * 2);     // enc_fcW^T
  size_t oWT6 = place(256 * 512 * 2);     // attn_We^T
  size_t oWcT = place(1024 * 256 * 2);    // [dec_Whh | attn_Wh]^T
  size_t oW7aT = place(768 * 320 * 2);    // dec_Wih[0:300]^T  [768][320]
  size_t oW7bT = place(1024 * 512 * 2);   // dec_Wih[300:812]^T perm1024
  size_t oW8aT = place(128 * 320 * 2);    // fcW[768:1068]^T (emb) [128][320]
  size_t oW8bT = place(128 * 768 * 2);    // fcW k-perm [weighted|hn] [128][768]
  size_t oB1 = place(768 * 2), oB2 = place(1024 * 2);
  size_t oB3 = place(768 * 2), oB4 = place(1024 * 2);
  size_t oB5 = place(256 * 2), oB6 = place(256 * 2);
  size_t oB7 = place(768 * 2), oBc = place(1024 * 2), oB8 = place(128 * 2);
  size_t o_wend = need;
  size_t o_bse = place((size_t)B * S * 512 * 2);
  size_t o_proj = place((size_t)B * S * 256 * 2);
  size_t o_ghw = place((size_t)B * 1024 * 2);
  size_t o_hfb = place((size_t)B * 512 * 4);
  size_t o_hb0 = place((size_t)B * 512 * 2);
  size_t o_hb1 = place((size_t)B * 512 * 2);
  size_t o_hd = place((size_t)B * 256 * 4);
  size_t o_hdbf = place((size_t)B * 256 * 2);
  size_t o_xgc = place((size_t)(T - 1) * B * 768 * 2);  // 75.5 MB
  size_t o_gtF = place(128 * 768 * 2);  // giTab fwd (64 used, pad 128)
  size_t o_gtB = place(128 * 768 * 2);
  size_t o_gtE = place(128 * 768 * 2);
  size_t o_fcT = place(128 * 128 * 4);  // f32 fc emb table

  if (ws_size < need) {
    sentinel_kernel<<<(out_size + 255) / 256, 256, 0, stream>>>(out, out_size);
    return;
  }

  char* base = (char*)d_ws;
  unsigned* dflag = (unsigned*)(base + o_flag);
  bf16* embE = (bf16*)(base + oEmbE);
  bf16* embD = (bf16*)(base + oEmbD);
  short* WT1 = (short*)(base + oWT1);
  short* WT2p = (short*)(base + oWT2);
  short* WT3 = (short*)(base + oWT3);
  short* WT4p = (short*)(base + oWT4);
  short* WT5 = (short*)(base + oWT5);
  short* WT6 = (short*)(base + oWT6);
  short* WcT = (short*)(base + oWcT);
  short* W7aT = (short*)(base + oW7aT);
  short* W7bTp = (short*)(base + oW7bT);
  short* W8aT = (short*)(base + oW8aT);
  short* W8bT = (short*)(base + oW8bT);
  bf16 *B1 = (bf16*)(base + oB1), *B2p = (bf16*)(base + oB2);
  bf16 *B3 = (bf16*)(base + oB3), *B4p = (bf16*)(base + oB4);
  bf16 *B5 = (bf16*)(base + oB5), *B6 = (bf16*)(base + oB6);
  bf16 *B7 = (bf16*)(base + oB7), *Bc = (bf16*)(base + oBc);
  bf16* B8 = (bf16*)(base + oB8);
  bf16* bse = (bf16*)(base + o_bse);
  bf16* proj = (bf16*)(base + o_proj);
  bf16* ghw = (bf16*)(base + o_ghw);
  float* hfb = (float*)(base + o_hfb);
  bf16* hb[2] = {(bf16*)(base + o_hb0), (bf16*)(base + o_hb1)};
  float* h_d = (float*)(base + o_hd);
  bf16* hdbf = (bf16*)(base + o_hdbf);
  bf16* xgcAll = (bf16*)(base + o_xgc);
  bf16* giTabF = (bf16*)(base + o_gtF);
  bf16* giTabB = (bf16*)(base + o_gtB);
  bf16* giTabE = (bf16*)(base + o_gtE);
  float* fcTab = (float*)(base + o_fcT);

  detect_kernel<<<1, 256, 0, stream>>>(enc_emb, dflag);
  (void)hipMemsetAsync(base + o_wstart, 0, o_wend - o_wstart, stream);

  // ---- weight prep ----
  PrepArgs pa;
  int ns = 0;
  long long tot = 0;
  auto seg = [&](const void* s, long long soff, short* dst, int scols,
                 int dstride, int transp, long long count) {
    pa.src[ns] = s;
    pa.soff[ns] = soff;
    pa.dst[ns] = dst;
    pa.scols[ns] = scols;
    pa.dstride[ns] = dstride;
    pa.transp[ns] = transp;
    pa.prefix[ns] = tot;
    tot += count;
    ns++;
  };
  seg(enc_emb, 0, (short*)embE, 300, 320, 0, 64 * 300);
  seg(dec_emb, 0, (short*)embD, 300, 320, 0, 128 * 300);
  seg(enc_Wih_f, 0, WT1, 768, 320, 1, 230400);
  seg(enc_Whh_f, 0, WT2p, 768, 256, 2, 196608);
  seg(enc_Wih_b, 0, WT3, 768, 320, 1, 230400);
  seg(enc_Whh_b, 0, WT4p, 768, 256, 2, 196608);
  seg(enc_fcW, 0, WT5, 256, 512, 1, 131072);
  seg(attn_We, 0, WT6, 256, 512, 1, 131072);
  seg(dec_Whh, 0, WcT, 768, 256, 1, 196608);
  seg(attn_Wh, 0, WcT + 768 * 256, 256, 256, 1, 65536);
  seg(dec_Wih, 0, W7aT, 768, 320, 1, 300 * 768);                     // 0:300
  seg(dec_Wih, (long long)300 * 768, W7bTp, 768, 512, 2, 512 * 768); // 300:812
  seg(fcW, (long long)768 * 128, W8aT, 128, 320, 1, 300 * 128);  // emb part
  seg(fcW, (long long)256 * 128, W8bT, 128, 768, 1, 512 * 128);  // weighted
  seg(fcW, 0, W8bT + 512, 128, 768, 1, 256 * 128);               // hn
  seg(enc_bih_f, 0, (short*)B1, 768, 768, 0, 768);
  seg(enc_bhh_f, 0, (short*)B2p, 768, 1024, 3, 768);
  seg(enc_bih_b, 0, (short*)B3, 768, 768, 0, 768);
  seg(enc_bhh_b, 0, (short*)B4p, 768, 1024, 3, 768);
  seg(enc_fcb, 0, (short*)B5, 256, 256, 0, 256);
  seg(attn_b, 0, (short*)B6, 256, 256, 0, 256);
  seg(dec_bih, 0, (short*)B7, 768, 768, 0, 768);
  seg(dec_bhh, 0, (short*)Bc, 768, 768, 0, 768);  // Bc[768:1024] stays 0
  seg(fcb, 0, (short*)B8, 128, 128, 0, 128);
  pa.prefix[ns] = tot;
  pa.nseg = ns;
  prep_kernel<<<(int)((tot + 255) / 256), 256, 0, stream>>>(pa, dflag);

  (void)hipMemsetAsync(hfb, 0, (size_t)B * 512 * 4, stream);
  (void)hipMemsetAsync(hb[0], 0, (size_t)B * 512 * 2, stream);
  (void)hipMemsetAsync(out, 0, (size_t)B * VOUT * 4, stream);  // outputs[0]=0

  auto launch = [&](const GJob* jobs, int nj, int gx, int gy) {
    GJobs a{};
    for (int i = 0; i < nj; i++) a.j[i] = jobs[i];
    mj_gemm<<<dim3(gx, gy, nj), 256, 0, stream>>>(a);
  };
  auto launchC = [&](const CJob* jobs, int nj) {
    CJobs a{};
    for (int i = 0; i < nj; i++) a.j[i] = jobs[i];
    mj_gemm_cell<<<dim3(8, 16, nj), 256, 0, stream>>>(a);
  };

  // ---- token tables: VIN=64 / VOUT=128 distinct rows only ----
  // M padded to 128 (embE rows 64:127 read garbage, outputs never gathered)
  {
    GJob tj[4];
    tj[0] = {embE, WT1, B1, nullptr, giTabF, nullptr, nullptr,
             320, 320, 320, 128, 768, 0};
    tj[1] = {embE, WT3, B3, nullptr, giTabB, nullptr, nullptr,
             320, 320, 320, 128, 768, 0};
    tj[2] = {embD, W7aT, B7, nullptr, giTabE, nullptr, nullptr,
             320, 320, 320, 128, 768, 0};
    tj[3] = {embD, W8aT, B8, fcTab, nullptr, nullptr, nullptr,
             320, 320, 320, 128, 128, 0};
    launch(tj, 4, 6, 1);
  }

  // ---- encoder: ONE fused launch per step (gh GEMM + GRU cell) ----
  // h ping-pongs between hb[0]/hb[1] (epilogue writes race-free vs A reads)
  for (int s = 0; s < S; s++) {
    CJob c[2];
    c[0] = {hb[s & 1], WT2p, B2p, nullptr, src + (size_t)s * B, giTabF,
            hfb, hb[(s + 1) & 1], bse + (size_t)s * 512, 12288,
            512, 256, 256, 512, 0};
    c[1] = {hb[s & 1] + 256, WT4p, B4p, nullptr,
            src + (size_t)(S - 1 - s) * B, giTabB,
            hfb, hb[(s + 1) & 1], bse + (size_t)(S - 1 - s) * 512 + 256, 12288,
            512, 256, 256, 512, 256};
    launchC(c, 2);
  }

  // hidden = tanh([h_f,h_b]@enc_fcW+b) -> h_d/hdbf; proj = bse@attn_We+attn_b
  {
    GJob mj[2];
    mj[0] = {hb[0], WT5, B5, h_d, hdbf, nullptr, nullptr,
             512, 512, 512, B, 256, 4};
    mj[1] = {bse, WT6, B6, nullptr, proj, nullptr, nullptr,
             512, 512, 512, B * S, 256, 0};
    launch(mj, 2, 2, 384);
  }

  // ---- decoder: attn -> fused(jw+cell) -> wc; logits batched at end ----
  auto wc_job = [&]() -> GJob {
    return {hdbf, WcT, Bc, nullptr, ghw, nullptr, nullptr,
            256, 256, 256, B, 1024, 0};
  };
  {
    GJob j0 = wc_job();
    launch(&j0, 1, 8, 16);
  }
  for (int t = 0; t < T - 1; t++) {
    bf16* xr = xgcAll + (size_t)t * B * 768;
    attn_kernel<<<B, 256, 0, stream>>>(ghw, proj, bse, attn_v, xr, dflag);
    CJob c = {xr, W7bTp, nullptr, ghw, trg + (size_t)t * B, giTabE,
              h_d, hdbf, xr + 512, 768, 768, 512, 512, 256, 0};
    launchC(&c, 1);
    if (t < T - 2) {
      GJob j0 = wc_job();
      launch(&j0, 1, 8, 16);
    }
  }
  // logits for all steps: out[t+1] = xgcAll[t] @ W8b + fcTab[trg[t]]
  {
    GJob jf = {xgcAll, W8bT, nullptr, out + (size_t)B * VOUT, nullptr,
               fcTab, trg, 768, 768, 768, (T - 1) * B, 128, 0};
    launch(&jf, 1, 1, 384);
  }
}